// Round 3
// baseline (53332.788 us; speedup 1.0000x reference)
//
#include <hip/hip_runtime.h>
#include <cstdint>

// Problem constants (from reference): I=256, H=1024, O=1, T=16384
#define I_DIM   256
#define H_DIM   1024
#define T_STEPS 16384
#define NBLK    128     // persistent blocks, 1 per CU (256 CUs -> 2x residency margin)
#define CELLS   8       // h cells per block  (128*8 = 1024)
#define THREADS 512     // 8 waves; wave wv owns cell wv; 16-lane group = gate

// Fast device math: v_exp_f32 / v_rcp_f32 based, ~1-2 ulp.
__device__ __forceinline__ float fast_sigmoid(float x) {
    return __builtin_amdgcn_rcpf(1.f + __expf(-x));
}
__device__ __forceinline__ float fast_tanh(float x) {
    const float a = fabsf(x);
    const float e = __expf(-2.f * a);
    const float t = (1.f - e) * __builtin_amdgcn_rcpf(1.f + e);
    return copysignf(t, x);
}

// ---------------------------------------------------------------------------
// Persistent LSTM scan kernel.
// Wave wv owns cell (blk*8+wv); 16-lane group q owns gate row q*H + blk*8 + wv.
// Weights in NAMED float4 registers (guaranteed SROA). h broadcast via a
// 2-slot global ring of (tag<<32 | float_bits) u64 words, agent-scope relaxed
// atomics (data IS the flag). ONE barrier per step: h_cur is double-buffered,
// and the ring's transitivity argument (poll success at t+2 implies all waves
// finished step t+1's reads) protects the t&1 LDS buffer reuse.
// ---------------------------------------------------------------------------
__launch_bounds__(THREADS, 1)
__global__ void lstm_persist(const float* __restrict__ x,
                             const float* __restrict__ W_ih,
                             const float* __restrict__ W_hh,
                             const float* __restrict__ b_ih,
                             const float* __restrict__ b_hh,
                             unsigned long long* __restrict__ ring)
{
    __shared__ __align__(16) float h_cur[2][H_DIM];
    __shared__ __align__(16) float xbuf[2][I_DIM];

    const int tid = threadIdx.x;
    const int blk = blockIdx.x;
    const int wv  = tid >> 6;           // wave id = cell within block (0..7)
    const int q   = (tid >> 4) & 3;     // 16-lane group = gate (i,f,g,o)
    const int l   = tid & 15;           // lane within group
    const int row_g = q * H_DIM + blk * CELLS + wv;   // global gate row

    // --- W_hh row slice in 16 NAMED float4 regs: lane l covers k = J*64 + l*4
    const float4* Wrow = reinterpret_cast<const float4*>(W_hh + (size_t)row_g * H_DIM);
    float4 wA0  = Wrow[ 0*16 + l], wA1  = Wrow[ 1*16 + l], wA2  = Wrow[ 2*16 + l], wA3  = Wrow[ 3*16 + l];
    float4 wA4  = Wrow[ 4*16 + l], wA5  = Wrow[ 5*16 + l], wA6  = Wrow[ 6*16 + l], wA7  = Wrow[ 7*16 + l];
    float4 wA8  = Wrow[ 8*16 + l], wA9  = Wrow[ 9*16 + l], wA10 = Wrow[10*16 + l], wA11 = Wrow[11*16 + l];
    float4 wA12 = Wrow[12*16 + l], wA13 = Wrow[13*16 + l], wA14 = Wrow[14*16 + l], wA15 = Wrow[15*16 + l];
    // --- W_ih row slice: lane l covers k = S*64 + l*4
    const float4* Vrow = reinterpret_cast<const float4*>(W_ih + (size_t)row_g * I_DIM);
    float4 wI0 = Vrow[0*16 + l], wI1 = Vrow[1*16 + l], wI2 = Vrow[2*16 + l], wI3 = Vrow[3*16 + l];
    const float bias_r = b_ih[row_g] + b_hh[row_g];

    // --- x_0 into xbuf[0]
    if (tid < 64)
        *reinterpret_cast<float4*>(&xbuf[0][tid * 4]) =
            *reinterpret_cast<const float4*>(x + tid * 4);
    __syncthreads();

#define XG_DOT(dst, buf)                                                              \
    {                                                                                 \
        const float4 x0 = *reinterpret_cast<const float4*>(&(buf)[0 * 64 + l * 4]);   \
        const float4 x1 = *reinterpret_cast<const float4*>(&(buf)[1 * 64 + l * 4]);   \
        const float4 x2 = *reinterpret_cast<const float4*>(&(buf)[2 * 64 + l * 4]);   \
        const float4 x3 = *reinterpret_cast<const float4*>(&(buf)[3 * 64 + l * 4]);   \
        dst += wI0.x * x0.x + wI0.y * x0.y + wI0.z * x0.z + wI0.w * x0.w;             \
        dst += wI1.x * x1.x + wI1.y * x1.y + wI1.z * x1.z + wI1.w * x1.w;             \
        dst += wI2.x * x2.x + wI2.y * x2.y + wI2.z * x2.z + wI2.w * x2.w;             \
        dst += wI3.x * x3.x + wI3.y * x3.y + wI3.z * x3.z + wI3.w * x3.w;             \
    }

    // xg partial for t=0 (bias folded in on lane 0 of each 16-lane group)
    float xg = (l == 0) ? bias_r : 0.f;
    XG_DOT(xg, xbuf[0]);

    // x_1 into xbuf[1]
    if (tid < 64)
        *reinterpret_cast<float4*>(&xbuf[1][tid * 4]) =
            *reinterpret_cast<const float4*>(x + I_DIM + tid * 4);
    int   cur     = 1;      // xbuf[cur] holds x_{t+1}
    float c_state = 0.f;    // cell state (replicated across the wave's 64 lanes)

    for (int t = 0; t < T_STEPS; ++t) {
        // (1) prefetch x_{t+2} into registers (consumed after the barrier)
        float4 xpre;
        if (tid < 64) {
            const int tt = (t + 2 < T_STEPS) ? t + 2 : T_STEPS - 1;
            xpre = *reinterpret_cast<const float4*>(x + (size_t)tt * I_DIM + tid * 4);
        }
        // (2) obtain h_{t-1}: poll own 2 words (tag==t-1 means valid)
        float2 hv;
        if (t == 0) {
            hv.x = 0.f; hv.y = 0.f;
        } else {
            const unsigned long long want = (unsigned long long)(t - 1);
            unsigned long long* p = ring + (((t - 1) & 1) ? H_DIM : 0) + 2 * tid;
            unsigned long long v0 = 0, v1 = 0;
            bool g0 = false, g1 = false;
            for (;;) {
                if (!g0) { v0 = __hip_atomic_load(p,     __ATOMIC_RELAXED, __HIP_MEMORY_SCOPE_AGENT); g0 = ((v0 >> 32) == want); }
                if (!g1) { v1 = __hip_atomic_load(p + 1, __ATOMIC_RELAXED, __HIP_MEMORY_SCOPE_AGENT); g1 = ((v1 >> 32) == want); }
                if (g0 && g1) break;
                __builtin_amdgcn_s_sleep(1);   // back off ~64cy: cut fabric contention
            }
            hv.x = __uint_as_float((unsigned)v0);
            hv.y = __uint_as_float((unsigned)v1);
        }
        float* hb = h_cur[t & 1];
        *reinterpret_cast<float2*>(&hb[2 * tid]) = hv;
        __syncthreads();    // the ONLY barrier per step

        // (3) rotate x double-buffer (safe: xbuf[cur^1] last read before this barrier)
        if (tid < 64)
            *reinterpret_cast<float4*>(&xbuf[cur ^ 1][tid * 4]) = xpre;

        // (4) recurrent dot: acc = xg_t + W_hh[row,:] . h_{t-1}
        float acc = xg;
#define HDOT(J, WREG)                                                                 \
        {                                                                             \
            const float4 h4 = *reinterpret_cast<const float4*>(&hb[(J) * 64 + l * 4]);\
            acc += WREG.x * h4.x + WREG.y * h4.y + WREG.z * h4.z + WREG.w * h4.w;     \
        }
        HDOT( 0, wA0)  HDOT( 1, wA1)  HDOT( 2, wA2)  HDOT( 3, wA3)
        HDOT( 4, wA4)  HDOT( 5, wA5)  HDOT( 6, wA6)  HDOT( 7, wA7)
        HDOT( 8, wA8)  HDOT( 9, wA9)  HDOT(10, wA10) HDOT(11, wA11)
        HDOT(12, wA12) HDOT(13, wA13) HDOT(14, wA14) HDOT(15, wA15)
#undef HDOT

        // (5) 16-lane butterfly -> row value uniform in each 16-lane group
        acc += __shfl_xor(acc, 1);
        acc += __shfl_xor(acc, 2);
        acc += __shfl_xor(acc, 4);
        acc += __shfl_xor(acc, 8);
        // (6) gather the 4 gate rows of this wave's cell (readlane, in-wave)
        const float gi_r = __shfl(acc, 0);
        const float gf_r = __shfl(acc, 16);
        const float gg_r = __shfl(acc, 32);
        const float go_r = __shfl(acc, 48);
        // (7) gate nonlinearities (fast-math; redundant on all 64 lanes)
        const float gi = fast_sigmoid(gi_r);
        const float gf = fast_sigmoid(gf_r);
        const float gg = fast_tanh(gg_r);
        const float go = fast_sigmoid(go_r);
        c_state = gf * c_state + gi * gg;
        const float h_new = go * fast_tanh(c_state);
        // (8) publish h_t ASAP (lane 0 of each wave)
        if ((tid & 63) == 0) {
            const unsigned long long pack =
                ((unsigned long long)t << 32) | (unsigned long long)__float_as_uint(h_new);
            __hip_atomic_store(ring + ((t & 1) ? H_DIM : 0) + blk * CELLS + wv, pack,
                               __ATOMIC_RELAXED, __HIP_MEMORY_SCOPE_AGENT);
        }

        // (9) off-critical-path: xg for t+1 (overlaps other blocks' polls)
        float xg_n = (l == 0) ? bias_r : 0.f;
        XG_DOT(xg_n, xbuf[cur]);
        xg = xg_n;
        cur ^= 1;
    }
#undef XG_DOT
}

// ---------------------------------------------------------------------------
// Final FFN: z = relu(h @ W1.T + b1);  partial_b = sum_j z_j * W2_j per block
// ---------------------------------------------------------------------------
__global__ void ffn_kernel(const unsigned long long* __restrict__ ring,
                           const float* __restrict__ W1,
                           const float* __restrict__ b1,
                           const float* __restrict__ W2,
                           float* __restrict__ partials)
{
    __shared__ float psum[8];
    const int tid = threadIdx.x;        // 256
    const int r2  = tid >> 5;           // 0..7
    const int l2  = tid & 31;
    const int j   = blockIdx.x * 8 + r2;
    const unsigned long long* hslot = ring + (((T_STEPS - 1) & 1) ? H_DIM : 0);

    float acc = 0.f;
    #pragma unroll 8
    for (int kk = 0; kk < 32; ++kk) {
        const int   k  = kk * 32 + l2;
        const float hk = __uint_as_float((unsigned)hslot[k]);
        acc += hk * W1[(size_t)j * H_DIM + k];
    }
    acc += __shfl_xor(acc, 1);
    acc += __shfl_xor(acc, 2);
    acc += __shfl_xor(acc, 4);
    acc += __shfl_xor(acc, 8);
    acc += __shfl_xor(acc, 16);
    if (l2 == 0) {
        float z = acc + b1[j];
        z = z > 0.f ? z : 0.f;
        psum[r2] = z * W2[j];
    }
    __syncthreads();
    if (tid == 0) {
        float s = 0.f;
        #pragma unroll
        for (int i = 0; i < 8; ++i) s += psum[i];
        partials[blockIdx.x] = s;
    }
}

__global__ void out_kernel(const float* __restrict__ partials,
                           const float* __restrict__ b2,
                           float* __restrict__ out)
{
    __shared__ float ws2[2];
    const int tid = threadIdx.x;        // 128
    float v = partials[tid];
    v += __shfl_xor(v, 1);
    v += __shfl_xor(v, 2);
    v += __shfl_xor(v, 4);
    v += __shfl_xor(v, 8);
    v += __shfl_xor(v, 16);
    v += __shfl_xor(v, 32);
    if ((tid & 63) == 0) ws2[tid >> 6] = v;
    __syncthreads();
    if (tid == 0) out[0] = ws2[0] + ws2[1] + b2[0];
}

extern "C" void kernel_launch(void* const* d_in, const int* in_sizes, int n_in,
                              void* d_out, int out_size, void* d_ws, size_t ws_size,
                              hipStream_t stream)
{
    const float* x    = (const float*)d_in[0];   // (1,T,I)
    const float* W_ih = (const float*)d_in[1];   // (4H,I)
    const float* W_hh = (const float*)d_in[2];   // (4H,H)
    const float* b_ih = (const float*)d_in[3];   // (4H)
    const float* b_hh = (const float*)d_in[4];   // (4H)
    const float* W1   = (const float*)d_in[5];   // (H,H)
    const float* b1   = (const float*)d_in[6];   // (H)
    const float* W2   = (const float*)d_in[7];   // (1,H)
    const float* b2   = (const float*)d_in[8];   // (1)
    float* out = (float*)d_out;

    unsigned long long* ring = (unsigned long long*)d_ws;         // 2*H u64 = 16 KiB
    const size_t ring_bytes = (size_t)2 * H_DIM * sizeof(unsigned long long);
    float* partials = (float*)((char*)d_ws + ring_bytes);         // 128 f32

    // Poison ring tags so stale tags from a previous replay can never match
    // (tag 0xAAAAAAAA != any step index). Harness also poisons ws to 0xAA.
    hipMemsetAsync(d_ws, 0xAA, ring_bytes, stream);

    lstm_persist<<<NBLK, THREADS, 0, stream>>>(x, W_ih, W_hh, b_ih, b_hh, ring);
    ffn_kernel<<<128, 256, 0, stream>>>(ring, W1, b1, W2, partials);
    out_kernel<<<1, 128, 0, stream>>>(partials, b2, out);
}